// Round 4
// baseline (161.942 us; speedup 1.0000x reference)
//
#include <hip/hip_runtime.h>

typedef __attribute__((ext_vector_type(8))) short short8;
typedef __attribute__((ext_vector_type(4))) float floatx4;

#define CIN  256
#define NSP  2048   // T*H*W
#define COUT 256

__device__ __forceinline__ unsigned short f2bf_rne(float f) {
  unsigned int u = __float_as_uint(f);
  u += 0x7fffu + ((u >> 16) & 1u);
  return (unsigned short)(u >> 16);
}

// pack two f32 -> bf16x2 (round-half-up) in 3 VALU
__device__ __forceinline__ unsigned int pack_bf16_hu(float lo, float hi) {
  unsigned int a = __float_as_uint(lo) + 0x8000u;
  unsigned int b = __float_as_uint(hi) + 0x8000u;
  return __builtin_amdgcn_perm(b, a, 0x07060302u);
}

// ---------------------------------------------------------------------------
// K1: M = Wout @ Wv (bf16). 64 blocks x 256 threads, 4 rows per block.
// Block reads Wv once (L2/L3-hot after first touch): 64x512KB = 33.5 MB agg.
// ---------------------------------------------------------------------------
__global__ __launch_bounds__(256) void k1_m(
    const float* __restrict__ Wv, const float* __restrict__ Wout,
    unsigned short* __restrict__ Mb)
{
  __shared__ float ws[4 * 512];
  const int tid = threadIdx.x;
  const int rbase = blockIdx.x * 4;
  #pragma unroll
  for (int i = 0; i < 8; ++i)
    ws[i * 256 + tid] = Wout[(size_t)rbase * 512 + i * 256 + tid];
  __syncthreads();
  float a4[4] = {0.f, 0.f, 0.f, 0.f};
  #pragma unroll 8
  for (int f = 0; f < 512; ++f) {
    float w = Wv[(size_t)f * 256 + tid];   // coalesced
    #pragma unroll
    for (int j = 0; j < 4; ++j) a4[j] += ws[j * 512 + f] * w;  // LDS broadcast
  }
  #pragma unroll
  for (int j = 0; j < 4; ++j)
    Mb[(size_t)(rbase + j) * 256 + tid] = f2bf_rne(a4[j]);
}

// ---------------------------------------------------------------------------
// K2: fused GEMM + bias + relu + residual + BN-stats + grid-barrier + norm.
// grid (16 nb, 2 ocb, 8 b) = 256 blocks (<= 256 CUs -> all co-resident);
// 512 threads = 8 waves; wave tile 64oc x 32n; y stays in registers across
// the stats barrier; out written exactly once.
// ---------------------------------------------------------------------------
__global__ __launch_bounds__(512, 2) void k2_fused(
    const float* __restrict__ x, const unsigned short* __restrict__ Mb,
    const float* __restrict__ bout, const float* __restrict__ gamma,
    const float* __restrict__ beta, float* __restrict__ stats,
    int* __restrict__ scount, float* __restrict__ out)
{
  __shared__ float ls[128], lq[128];
  const int tid  = threadIdx.x;
  const int lane = tid & 63;
  const int wave = tid >> 6;
  const int m16  = lane & 15;
  const int q    = lane >> 4;
  const int nb   = blockIdx.x * 128;
  const int ocb  = blockIdx.y * 128;
  const int b    = blockIdx.z;
  const int wocb = ocb + (wave & 1) * 64;    // wave's 64 oc rows
  const int wnb  = nb + (wave >> 1) * 32;    // wave's 32 n cols

  if (tid < 128) { ls[tid] = 0.f; lq[tid] = 0.f; }

  // ---- pack all B fragments in-register (x f32 -> bf16), no LDS ----
  const float* Bb = x + (size_t)b * CIN * NSP + (size_t)(q * 8) * NSP + wnb + m16;
  short8 bv[8][2];                            // 64 VGPRs
  #pragma unroll
  for (int kk = 0; kk < 8; ++kk) {
    #pragma unroll
    for (int tj = 0; tj < 2; ++tj) {
      const float* bp = Bb + (size_t)(kk * 32) * NSP + tj * 16;
      union { unsigned int u[4]; short8 v; } p;
      #pragma unroll
      for (int j = 0; j < 4; ++j) {
        float f0 = bp[(size_t)(2 * j) * NSP];
        float f1 = bp[(size_t)(2 * j + 1) * NSP];
        p.u[j] = pack_bf16_hu(f0, f1);
      }
      bv[kk][tj] = p.v;
    }
  }

  // ---- MFMA: A streamed from L2-hot Mb ----
  floatx4 acc[4][2];
  #pragma unroll
  for (int i = 0; i < 4; ++i)
    #pragma unroll
    for (int j = 0; j < 2; ++j)
      acc[i][j] = (floatx4){0.f, 0.f, 0.f, 0.f};

  const unsigned short* Ab = Mb + (size_t)(wocb + m16) * 256 + q * 8;
  #pragma unroll
  for (int kk = 0; kk < 8; ++kk) {
    short8 av[4];
    #pragma unroll
    for (int ti = 0; ti < 4; ++ti)
      av[ti] = *(const short8*)(Ab + (size_t)ti * 16 * 256 + kk * 32);
    #pragma unroll
    for (int ti = 0; ti < 4; ++ti)
      #pragma unroll
      for (int tj = 0; tj < 2; ++tj)
        acc[ti][tj] = __builtin_amdgcn_mfma_f32_16x16x32_bf16(av[ti], bv[kk][tj], acc[ti][tj], 0, 0, 0);
  }

  __syncthreads();  // ls/lq zeros ready

  // ---- epilogue pass 1: bias+relu+residual, y -> acc, stats partials ----
  // D layout: col(n)=lane&15, row(oc within 16-tile)=q*4+reg
  #pragma unroll
  for (int ti = 0; ti < 4; ++ti) {
    #pragma unroll
    for (int r = 0; r < 4; ++r) {
      const int ocl = (wave & 1) * 64 + ti * 16 + q * 4 + r;
      const int oc  = ocb + ocl;
      const float bo = bout[oc];
      float s = 0.f, s2 = 0.f;
      #pragma unroll
      for (int tj = 0; tj < 2; ++tj) {
        const int n = wnb + tj * 16 + m16;
        const size_t gidx = ((size_t)(b * COUT + oc)) * NSP + n;
        float o = fmaxf(acc[ti][tj][r] + bo, 0.f);
        float y = x[gidx] + o;      // residual row is L1-hot (B-pack touched it)
        acc[ti][tj][r] = y;         // keep y resident
        s += y;
        s2 += y * y;
      }
      #pragma unroll
      for (int d = 1; d < 16; d <<= 1) {
        s  += __shfl_xor(s, d, 64);
        s2 += __shfl_xor(s2, d, 64);
      }
      if (m16 == 0) {
        atomicAdd(&ls[ocl], s);
        atomicAdd(&lq[ocl], s2);
      }
    }
  }
  __syncthreads();
  if (tid < 128) {
    atomicAdd(&stats[ocb + tid], ls[tid]);
    atomicAdd(&stats[256 + ocb + tid], lq[tid]);
  }

  // ---- software grid barrier (all 256 blocks co-resident by construction) --
  __threadfence();
  __syncthreads();
  if (tid == 0) {
    __hip_atomic_fetch_add(scount, 1, __ATOMIC_ACQ_REL, __HIP_MEMORY_SCOPE_AGENT);
    while (__hip_atomic_load(scount, __ATOMIC_ACQUIRE, __HIP_MEMORY_SCOPE_AGENT) < 256)
      __builtin_amdgcn_s_sleep(2);
  }
  __syncthreads();

  // ---- finalize scale/shift (coherent atomic loads), normalize, write ----
  if (tid < 128) {
    const int oc = ocb + tid;
    const float inv_n = 1.f / 16384.f;
    float sm = __hip_atomic_load(&stats[oc], __ATOMIC_RELAXED, __HIP_MEMORY_SCOPE_AGENT);
    float sq = __hip_atomic_load(&stats[256 + oc], __ATOMIC_RELAXED, __HIP_MEMORY_SCOPE_AGENT);
    float m = sm * inv_n;
    float v = sq * inv_n - m * m;
    float sc = gamma[oc] * rsqrtf(v + 1e-5f);
    ls[tid] = sc;
    lq[tid] = beta[oc] - m * sc;
  }
  __syncthreads();

  #pragma unroll
  for (int ti = 0; ti < 4; ++ti) {
    #pragma unroll
    for (int r = 0; r < 4; ++r) {
      const int ocl = (wave & 1) * 64 + ti * 16 + q * 4 + r;
      const int oc  = ocb + ocl;
      const float sc = ls[ocl];
      const float sh = lq[ocl];
      #pragma unroll
      for (int tj = 0; tj < 2; ++tj) {
        const int n = wnb + tj * 16 + m16;
        const size_t gidx = ((size_t)(b * COUT + oc)) * NSP + n;
        out[gidx] = acc[ti][tj][r] * sc + sh;
      }
    }
  }
}

extern "C" void kernel_launch(void* const* d_in, const int* in_sizes, int n_in,
                              void* d_out, int out_size, void* d_ws, size_t ws_size,
                              hipStream_t stream) {
  const float* x     = (const float*)d_in[0];
  // d_in[1]=Wk, d_in[2]=Wq: dead — softmax rows sum to 1, so agg == V and
  // o = Wout@(Wv@x) = (Wout@Wv)@x = M@x.
  const float* Wv    = (const float*)d_in[3];
  const float* Wout  = (const float*)d_in[4];
  const float* bout  = (const float*)d_in[5];
  const float* gamma = (const float*)d_in[6];
  const float* beta  = (const float*)d_in[7];
  float* out = (float*)d_out;

  char* w = (char*)d_ws;
  unsigned short* Mb = (unsigned short*)w;      // 128 KiB bf16 M
  float* stats = (float*)(w + 131072);          // 512 f32 sums
  int* scount  = (int*)(w + 131072 + 2048);     // barrier counter

  // zero stats + counter (graph-capturable memset node; re-runs every replay)
  hipMemsetAsync(stats, 0, 4096, stream);

  hipLaunchKernelGGL(k1_m, dim3(64), dim3(256), 0, stream, Wv, Wout, Mb);
  hipLaunchKernelGGL(k2_fused, dim3(16, 2, 8), dim3(512), 0, stream,
                     x, Mb, bout, gamma, beta, stats, scount, out);
}

// Round 5
// 139.896 us; speedup vs baseline: 1.1576x; 1.1576x over previous
//
#include <hip/hip_runtime.h>

typedef __attribute__((ext_vector_type(8))) short short8;
typedef __attribute__((ext_vector_type(4))) float floatx4;

#define CIN  256
#define NSP  2048   // T*H*W
#define COUT 256

__device__ __forceinline__ unsigned short f2bf_rne(float f) {
  unsigned int u = __float_as_uint(f);
  u += 0x7fffu + ((u >> 16) & 1u);
  return (unsigned short)(u >> 16);
}

// pack two f32 -> bf16x2 (round-half-up) in 3 VALU
__device__ __forceinline__ unsigned int pack_bf16_hu(float lo, float hi) {
  unsigned int a = __float_as_uint(lo) + 0x8000u;
  unsigned int b = __float_as_uint(hi) + 0x8000u;
  return __builtin_amdgcn_perm(b, a, 0x07060302u);
}

// ---------------------------------------------------------------------------
// K1: M = Wout @ Wv (bf16). 64 blocks x 256 threads, 4 rows per block.
// Block 0 zeroes the BN stats accumulators (k2 depends via stream order).
// ---------------------------------------------------------------------------
__global__ __launch_bounds__(256) void k1_m(
    const float* __restrict__ Wv, const float* __restrict__ Wout,
    unsigned short* __restrict__ Mb, float* __restrict__ stats)
{
  __shared__ float ws[4 * 512];
  const int tid = threadIdx.x;
  const int rbase = blockIdx.x * 4;
  if (blockIdx.x == 0) { stats[tid] = 0.f; stats[256 + tid] = 0.f; }
  #pragma unroll
  for (int i = 0; i < 8; ++i)
    ws[i * 256 + tid] = Wout[(size_t)rbase * 512 + i * 256 + tid];
  __syncthreads();
  float a4[4] = {0.f, 0.f, 0.f, 0.f};
  #pragma unroll 8
  for (int f = 0; f < 512; ++f) {
    float w = Wv[(size_t)f * 256 + tid];   // coalesced, L2-hot
    #pragma unroll
    for (int j = 0; j < 4; ++j) a4[j] += ws[j * 512 + f] * w;  // LDS broadcast
  }
  #pragma unroll
  for (int j = 0; j < 4; ++j)
    Mb[(size_t)(rbase + j) * 256 + tid] = f2bf_rne(a4[j]);
}

// ---------------------------------------------------------------------------
// K2: o = M @ x via bf16 MFMA, B-fragments packed in-register from f32 x.
// Fused bias+relu+residual; y -> bf16 workspace; BN partial sums -> stats.
// grid (64 nb, 2 ocb, 8 b) = 1024 blocks; 256 thr = 4 waves; 4 blocks/CU
// (16 waves/CU) for latency hiding. Wave tile 64oc x 16n, K=256 unrolled.
// ---------------------------------------------------------------------------
__global__ __launch_bounds__(256, 4) void k2_gemm(
    const float* __restrict__ x, const unsigned short* __restrict__ Mb,
    const float* __restrict__ bout, float* __restrict__ stats,
    unsigned short* __restrict__ ybf)
{
  __shared__ float ls[128], lq[128];
  const int tid  = threadIdx.x;
  const int lane = tid & 63;
  const int wave = tid >> 6;
  const int m16  = lane & 15;
  const int q    = lane >> 4;
  const int nb   = blockIdx.x * 32;
  const int ocb  = blockIdx.y * 128;
  const int b    = blockIdx.z;
  const int wocb = ocb + (wave & 1) * 64;   // wave's 64 oc rows
  const int wn   = nb + (wave >> 1) * 16;   // wave's 16 n cols

  if (tid < 128) { ls[tid] = 0.f; lq[tid] = 0.f; }

  floatx4 acc[4];
  #pragma unroll
  for (int i = 0; i < 4; ++i) acc[i] = (floatx4){0.f, 0.f, 0.f, 0.f};

  const unsigned short* Ab = Mb + (size_t)(wocb + m16) * 256 + q * 8;
  const float* Bb = x + (size_t)b * CIN * NSP + (size_t)(q * 8) * NSP + wn + m16;

  #pragma unroll
  for (int kk = 0; kk < 8; ++kk) {
    // B fragment: c = kk*32 + q*8 + j, at this lane's n column
    const float* bp = Bb + (size_t)(kk * 32) * NSP;
    union { unsigned int u[4]; short8 v; } p;
    #pragma unroll
    for (int j = 0; j < 4; ++j) {
      float f0 = bp[(size_t)(2 * j) * NSP];
      float f1 = bp[(size_t)(2 * j + 1) * NSP];
      p.u[j] = pack_bf16_hu(f0, f1);
    }
    #pragma unroll
    for (int ti = 0; ti < 4; ++ti) {
      short8 av = *(const short8*)(Ab + (size_t)ti * 16 * 256 + kk * 32);
      acc[ti] = __builtin_amdgcn_mfma_f32_16x16x32_bf16(av, p.v, acc[ti], 0, 0, 0);
    }
  }

  __syncthreads();  // ls/lq zeros ready

  // D layout: col(n) = lane&15, row(oc within 16-tile) = q*4 + reg
  const int n = wn + m16;
  #pragma unroll
  for (int ti = 0; ti < 4; ++ti) {
    #pragma unroll
    for (int r = 0; r < 4; ++r) {
      const int ocl = (wave & 1) * 64 + ti * 16 + q * 4 + r;
      const int oc  = ocb + ocl;
      const size_t gidx = ((size_t)(b * COUT + oc)) * NSP + n;
      float o = fmaxf(acc[ti][r] + bout[oc], 0.f);
      float y = x[gidx] + o;        // residual row is L1/L2-hot (B-pack)
      ybf[gidx] = f2bf_rne(y);
      float s = y, s2 = y * y;
      #pragma unroll
      for (int d = 1; d < 16; d <<= 1) {  // reduce over the 16 n-lanes
        s  += __shfl_xor(s, d, 64);
        s2 += __shfl_xor(s2, d, 64);
      }
      if (m16 == 0) {
        atomicAdd(&ls[ocl], s);
        atomicAdd(&lq[ocl], s2);
      }
    }
  }
  __syncthreads();
  if (tid < 128) {
    atomicAdd(&stats[ocb + tid], ls[tid]);
    atomicAdd(&stats[256 + ocb + tid], lq[tid]);
  }
}

// ---------------------------------------------------------------------------
// K3: out = y*scale + shift. 2048 blocks = one (b,oc) row each; y read as
// bf16 (L3-hot), out written f32. Scale/shift recomputed per block (scalar
// broadcast loads).
// ---------------------------------------------------------------------------
__global__ __launch_bounds__(256) void k3_norm(
    const float* __restrict__ stats, const float* __restrict__ gamma,
    const float* __restrict__ beta, const unsigned short* __restrict__ ybf,
    float* __restrict__ out)
{
  const int row = blockIdx.x;       // b*256 + oc
  const int oc  = row & 255;
  const float inv_n = 1.f / 16384.f;
  const float m  = stats[oc] * inv_n;
  const float v  = stats[256 + oc] * inv_n - m * m;
  const float sc = gamma[oc] * rsqrtf(v + 1e-5f);
  const float sh = beta[oc] - m * sc;
  const size_t base = (size_t)row * 2048 + threadIdx.x * 8;
  const uint4 raw = *(const uint4*)(ybf + base);
  float4 o0, o1;
  o0.x = __uint_as_float(raw.x << 16)         * sc + sh;
  o0.y = __uint_as_float(raw.x & 0xffff0000u) * sc + sh;
  o0.z = __uint_as_float(raw.y << 16)         * sc + sh;
  o0.w = __uint_as_float(raw.y & 0xffff0000u) * sc + sh;
  o1.x = __uint_as_float(raw.z << 16)         * sc + sh;
  o1.y = __uint_as_float(raw.z & 0xffff0000u) * sc + sh;
  o1.z = __uint_as_float(raw.w << 16)         * sc + sh;
  o1.w = __uint_as_float(raw.w & 0xffff0000u) * sc + sh;
  *(float4*)(out + base)     = o0;
  *(float4*)(out + base + 4) = o1;
}

extern "C" void kernel_launch(void* const* d_in, const int* in_sizes, int n_in,
                              void* d_out, int out_size, void* d_ws, size_t ws_size,
                              hipStream_t stream) {
  const float* x     = (const float*)d_in[0];
  // d_in[1]=Wk, d_in[2]=Wq: dead — softmax rows sum to 1, so agg == V and
  // o = Wout@(Wv@x) = (Wout@Wv)@x = M@x.
  const float* Wv    = (const float*)d_in[3];
  const float* Wout  = (const float*)d_in[4];
  const float* bout  = (const float*)d_in[5];
  const float* gamma = (const float*)d_in[6];
  const float* beta  = (const float*)d_in[7];
  float* out = (float*)d_out;

  char* w = (char*)d_ws;
  unsigned short* Mb = (unsigned short*)w;            // 128 KiB bf16 M
  float* stats = (float*)(w + 131072);                // 512 f32 sums
  unsigned short* ybf = (unsigned short*)(w + 131072 + 4096);  // 8.4 MiB bf16 y

  hipLaunchKernelGGL(k1_m,    dim3(64),        dim3(256), 0, stream,
                     Wv, Wout, Mb, stats);
  hipLaunchKernelGGL(k2_gemm, dim3(64, 2, 8),  dim3(256), 0, stream,
                     x, Mb, bout, stats, ybf);
  hipLaunchKernelGGL(k3_norm, dim3(2048),      dim3(256), 0, stream,
                     stats, gamma, beta, ybf, out);
}

// Round 6
// 125.271 us; speedup vs baseline: 1.2927x; 1.1167x over previous
//
#include <hip/hip_runtime.h>

typedef __attribute__((ext_vector_type(8))) short short8;
typedef __attribute__((ext_vector_type(4))) float floatx4;

#define CIN  256
#define NSP  2048   // T*H*W
#define COUT 256

__device__ __forceinline__ unsigned short f2bf_rne(float f) {
  unsigned int u = __float_as_uint(f);
  u += 0x7fffu + ((u >> 16) & 1u);
  return (unsigned short)(u >> 16);
}

// pack two f32 -> bf16x2 (round-half-up) in 3 VALU
__device__ __forceinline__ unsigned int pack_bf16_hu(float lo, float hi) {
  unsigned int a = __float_as_uint(lo) + 0x8000u;
  unsigned int b = __float_as_uint(hi) + 0x8000u;
  return __builtin_amdgcn_perm(b, a, 0x07060302u);
}

// ---------------------------------------------------------------------------
// K1: M = Wout @ Wv (bf16). 64 blocks x 256 threads, 4 rows per block.
// Block 0 zeroes the BN stats accumulators. (Validated ~free in round 4.)
// ---------------------------------------------------------------------------
__global__ __launch_bounds__(256) void k1_m(
    const float* __restrict__ Wv, const float* __restrict__ Wout,
    unsigned short* __restrict__ Mb, float* __restrict__ stats)
{
  __shared__ float ws[4 * 512];
  const int tid = threadIdx.x;
  const int rbase = blockIdx.x * 4;
  if (blockIdx.x == 0) { stats[tid] = 0.f; stats[256 + tid] = 0.f; }
  #pragma unroll
  for (int i = 0; i < 8; ++i)
    ws[i * 256 + tid] = Wout[(size_t)rbase * 512 + i * 256 + tid];
  __syncthreads();
  float a4[4] = {0.f, 0.f, 0.f, 0.f};
  #pragma unroll 8
  for (int f = 0; f < 512; ++f) {
    float w = Wv[(size_t)f * 256 + tid];   // coalesced, L2-hot
    #pragma unroll
    for (int j = 0; j < 4; ++j) a4[j] += ws[j * 512 + f] * w;  // LDS broadcast
  }
  #pragma unroll
  for (int j = 0; j < 4; ++j)
    Mb[(size_t)(rbase + j) * 256 + tid] = f2bf_rne(a4[j]);
}

// ---------------------------------------------------------------------------
// K2: round-3 tiling verbatim (proven best): grid (32 nb, 2 ocb, 8 b) = 512
// blocks, 256 thr = 4 waves, wave tile 64oc x 32n, K=256 fully unrolled,
// B-fragments packed in-register from f32 x. Only delta vs round 3: y is
// stored as bf16 to workspace (halves store traffic).
// ---------------------------------------------------------------------------
__global__ __launch_bounds__(256) void k2_gemm(
    const float* __restrict__ x, const unsigned short* __restrict__ Mb,
    const float* __restrict__ bout, float* __restrict__ stats,
    unsigned short* __restrict__ ybf)
{
  __shared__ float ls[128], lq[128];
  const int tid  = threadIdx.x;
  const int lane = tid & 63;
  const int wave = tid >> 6;
  const int m16  = lane & 15;
  const int q    = lane >> 4;
  const int nb   = blockIdx.x * 64;
  const int ocb  = blockIdx.y * 128;
  const int b    = blockIdx.z;
  const int wocb = ocb + (wave & 1) * 64;   // wave's 64 oc rows
  const int wnb  = nb + (wave >> 1) * 32;   // wave's 32 n cols

  if (tid < 128) { ls[tid] = 0.f; lq[tid] = 0.f; }

  floatx4 acc[4][2];
  #pragma unroll
  for (int i = 0; i < 4; ++i)
    #pragma unroll
    for (int j = 0; j < 2; ++j)
      acc[i][j] = (floatx4){0.f, 0.f, 0.f, 0.f};

  const unsigned short* Ab = Mb + (size_t)(wocb + m16) * 256 + q * 8;
  const float* xb = x + (size_t)b * CIN * NSP;
  const float* Bb = xb + (size_t)(q * 8) * NSP + wnb + m16;

  #pragma unroll
  for (int kk = 0; kk < 8; ++kk) {
    short8 av[4];
    #pragma unroll
    for (int ti = 0; ti < 4; ++ti)
      av[ti] = *(const short8*)(Ab + (size_t)ti * 16 * 256 + kk * 32);
    short8 bv[2];
    #pragma unroll
    for (int tj = 0; tj < 2; ++tj) {
      const float* bp = Bb + (size_t)(kk * 32) * NSP + tj * 16;
      union { unsigned int u[4]; short8 v; } p;
      #pragma unroll
      for (int j = 0; j < 4; ++j) {
        float f0 = bp[(size_t)(2 * j) * NSP];       // c = kk*32+q*8+2j
        float f1 = bp[(size_t)(2 * j + 1) * NSP];
        p.u[j] = pack_bf16_hu(f0, f1);
      }
      bv[tj] = p.v;
    }
    #pragma unroll
    for (int ti = 0; ti < 4; ++ti)
      #pragma unroll
      for (int tj = 0; tj < 2; ++tj)
        acc[ti][tj] = __builtin_amdgcn_mfma_f32_16x16x32_bf16(av[ti], bv[tj], acc[ti][tj], 0, 0, 0);
  }

  __syncthreads();  // ls/lq zeros ready

  // D layout: col(n)=lane&15, row(oc within 16-tile)=q*4+reg
  #pragma unroll
  for (int ti = 0; ti < 4; ++ti) {
    #pragma unroll
    for (int r = 0; r < 4; ++r) {
      const int ocl = (wave & 1) * 64 + ti * 16 + q * 4 + r;
      const int oc  = ocb + ocl;
      const float bo = bout[oc];
      float s = 0.f, s2 = 0.f;
      #pragma unroll
      for (int tj = 0; tj < 2; ++tj) {
        const int n = wnb + tj * 16 + m16;
        const size_t gidx = ((size_t)(b * COUT + oc)) * NSP + n;
        float o = fmaxf(acc[ti][tj][r] + bo, 0.f);
        float y = x[gidx] + o;        // residual row is L1/L2-hot (B-pack)
        ybf[gidx] = f2bf_rne(y);      // bf16 store: half the write traffic
        s += y;
        s2 += y * y;
      }
      #pragma unroll
      for (int d = 1; d < 16; d <<= 1) {  // reduce over the 16 n-lanes
        s  += __shfl_xor(s, d, 64);
        s2 += __shfl_xor(s2, d, 64);
      }
      if (m16 == 0) {
        atomicAdd(&ls[ocl], s);
        atomicAdd(&lq[ocl], s2);
      }
    }
  }
  __syncthreads();
  if (tid < 128) {
    atomicAdd(&stats[ocb + tid], ls[tid]);
    atomicAdd(&stats[256 + ocb + tid], lq[tid]);
  }
}

// ---------------------------------------------------------------------------
// K3: out = y*scale + shift. 2048 blocks = one (b,oc) row each; y read as
// bf16 (L3-hot), out written f32. Scale/shift recomputed per block.
// ---------------------------------------------------------------------------
__global__ __launch_bounds__(256) void k3_norm(
    const float* __restrict__ stats, const float* __restrict__ gamma,
    const float* __restrict__ beta, const unsigned short* __restrict__ ybf,
    float* __restrict__ out)
{
  const int row = blockIdx.x;       // b*256 + oc
  const int oc  = row & 255;
  const float inv_n = 1.f / 16384.f;
  const float m  = stats[oc] * inv_n;
  const float v  = stats[256 + oc] * inv_n - m * m;
  const float sc = gamma[oc] * rsqrtf(v + 1e-5f);
  const float sh = beta[oc] - m * sc;
  const size_t base = (size_t)row * 2048 + threadIdx.x * 8;
  const uint4 raw = *(const uint4*)(ybf + base);
  float4 o0, o1;
  o0.x = __uint_as_float(raw.x << 16)         * sc + sh;
  o0.y = __uint_as_float(raw.x & 0xffff0000u) * sc + sh;
  o0.z = __uint_as_float(raw.y << 16)         * sc + sh;
  o0.w = __uint_as_float(raw.y & 0xffff0000u) * sc + sh;
  o1.x = __uint_as_float(raw.z << 16)         * sc + sh;
  o1.y = __uint_as_float(raw.z & 0xffff0000u) * sc + sh;
  o1.z = __uint_as_float(raw.w << 16)         * sc + sh;
  o1.w = __uint_as_float(raw.w & 0xffff0000u) * sc + sh;
  *(float4*)(out + base)     = o0;
  *(float4*)(out + base + 4) = o1;
}

extern "C" void kernel_launch(void* const* d_in, const int* in_sizes, int n_in,
                              void* d_out, int out_size, void* d_ws, size_t ws_size,
                              hipStream_t stream) {
  const float* x     = (const float*)d_in[0];
  // d_in[1]=Wk, d_in[2]=Wq: dead — softmax rows sum to 1, so agg == V and
  // o = Wout@(Wv@x) = (Wout@Wv)@x = M@x.
  const float* Wv    = (const float*)d_in[3];
  const float* Wout  = (const float*)d_in[4];
  const float* bout  = (const float*)d_in[5];
  const float* gamma = (const float*)d_in[6];
  const float* beta  = (const float*)d_in[7];
  float* out = (float*)d_out;

  char* w = (char*)d_ws;
  unsigned short* Mb = (unsigned short*)w;                     // 128 KiB bf16 M
  float* stats = (float*)(w + 131072);                         // 512 f32 sums
  unsigned short* ybf = (unsigned short*)(w + 131072 + 4096);  // 8.4 MiB bf16 y

  hipLaunchKernelGGL(k1_m,    dim3(64),       dim3(256), 0, stream,
                     Wv, Wout, Mb, stats);
  hipLaunchKernelGGL(k2_gemm, dim3(32, 2, 8), dim3(256), 0, stream,
                     x, Mb, bout, stats, ybf);
  hipLaunchKernelGGL(k3_norm, dim3(2048),     dim3(256), 0, stream,
                     stats, gamma, beta, ybf, out);
}

// Round 7
// 113.341 us; speedup vs baseline: 1.4288x; 1.1053x over previous
//
#include <hip/hip_runtime.h>

typedef __attribute__((ext_vector_type(8))) short short8;
typedef __attribute__((ext_vector_type(4))) float floatx4;

#define CIN  256
#define NSP  2048   // T*H*W
#define COUT 256

__device__ __forceinline__ unsigned short f2bf_rne(float f) {
  unsigned int u = __float_as_uint(f);
  u += 0x7fffu + ((u >> 16) & 1u);
  return (unsigned short)(u >> 16);
}

// pack two f32 -> bf16x2 (round-half-up: +0x8000 then take hi16) in 3 VALU
__device__ __forceinline__ unsigned int pack_bf16_hu(float lo, float hi) {
  unsigned int a = __float_as_uint(lo) + 0x8000u;
  unsigned int b = __float_as_uint(hi) + 0x8000u;
  return __builtin_amdgcn_perm(b, a, 0x07060302u);
}

// ---------------------------------------------------------------------------
// K1: M = Wout @ Wv (bf16). 256 blocks (1 row each) x 1024 threads.
// Waves split the f(=512) reduction 4 ways; LDS reduce. Block 0 zeroes stats.
// ---------------------------------------------------------------------------
__global__ __launch_bounds__(1024) void k1_m(
    const float* __restrict__ Wv, const float* __restrict__ Wout,
    unsigned short* __restrict__ Mb, float* __restrict__ stats)
{
  __shared__ float ws[512];
  __shared__ float red[4][256];
  const int tid = threadIdx.x;
  const int r   = blockIdx.x;
  if (r == 0 && tid < 512) stats[tid] = 0.f;
  if (tid < 512) ws[tid] = Wout[(size_t)r * 512 + tid];
  __syncthreads();
  const int c  = tid & 255;
  const int fs = tid >> 8;            // constant per wave -> ws[f] broadcast
  float acc = 0.f;
  #pragma unroll 16
  for (int f0 = 0; f0 < 128; ++f0) {
    int f = fs * 128 + f0;
    acc += ws[f] * Wv[(size_t)f * 256 + c];   // coalesced, L2-hot
  }
  red[fs][c] = acc;
  __syncthreads();
  if (tid < 256) {
    float s = red[0][tid] + red[1][tid] + red[2][tid] + red[3][tid];
    Mb[(size_t)r * 256 + tid] = f2bf_rne(s);
  }
}

// ---------------------------------------------------------------------------
// K2: o = M @ x per batch via bf16 MFMA; B-fragments built in-register from
// f32 x (no transpose pass, no LDS staging, no K-loop barriers).
// Fused bias+relu+residual; f32 y -> out (d_out); BN partial sums -> stats.
// grid (32 nb, 2 ocb, 8 b) = 512 blocks; block = 4 waves; wave tile 64oc x 32n.
// ---------------------------------------------------------------------------
__global__ __launch_bounds__(256) void k2_gemm(
    const float* __restrict__ x, const unsigned short* __restrict__ Mb,
    const float* __restrict__ bout, float* __restrict__ stats,
    float* __restrict__ out)
{
  __shared__ float ls[128], lq[128];
  const int tid  = threadIdx.x;
  const int lane = tid & 63;
  const int wave = tid >> 6;
  const int m16  = lane & 15;
  const int q    = lane >> 4;
  const int nb   = blockIdx.x * 64;
  const int ocb  = blockIdx.y * 128;
  const int b    = blockIdx.z;
  const int wocb = ocb + (wave & 1) * 64;   // wave's 64 oc rows
  const int wnb  = nb + (wave >> 1) * 32;   // wave's 32 n cols

  if (tid < 128) { ls[tid] = 0.f; lq[tid] = 0.f; }

  floatx4 acc[4][2];
  #pragma unroll
  for (int i = 0; i < 4; ++i)
    #pragma unroll
    for (int j = 0; j < 2; ++j)
      acc[i][j] = (floatx4){0.f, 0.f, 0.f, 0.f};

  const unsigned short* Ab = Mb + (size_t)(wocb + m16) * 256 + q * 8;
  const float* xb = x + (size_t)b * CIN * NSP;
  const float* Bb = xb + (size_t)(q * 8) * NSP + wnb + m16;

  #pragma unroll
  for (int kk = 0; kk < 8; ++kk) {
    short8 av[4];
    #pragma unroll
    for (int ti = 0; ti < 4; ++ti)
      av[ti] = *(const short8*)(Ab + (size_t)ti * 16 * 256 + kk * 32);
    short8 bv[2];
    #pragma unroll
    for (int tj = 0; tj < 2; ++tj) {
      const float* bp = Bb + (size_t)(kk * 32) * NSP + tj * 16;
      union { unsigned int u[4]; short8 v; } p;
      #pragma unroll
      for (int j = 0; j < 4; ++j) {
        float f0 = bp[(size_t)(2 * j) * NSP];       // c = kk*32+q*8+2j
        float f1 = bp[(size_t)(2 * j + 1) * NSP];
        p.u[j] = pack_bf16_hu(f0, f1);
      }
      bv[tj] = p.v;
    }
    #pragma unroll
    for (int ti = 0; ti < 4; ++ti)
      #pragma unroll
      for (int tj = 0; tj < 2; ++tj)
        acc[ti][tj] = __builtin_amdgcn_mfma_f32_16x16x32_bf16(av[ti], bv[tj], acc[ti][tj], 0, 0, 0);
  }

  __syncthreads();  // ls/lq zeros ready

  // D layout: col(n)=lane&15, row(oc within 16-tile)=q*4+reg
  #pragma unroll
  for (int ti = 0; ti < 4; ++ti) {
    #pragma unroll
    for (int r = 0; r < 4; ++r) {
      const int ocl = (wave & 1) * 64 + ti * 16 + q * 4 + r;
      const int oc  = ocb + ocl;
      const float bo = bout[oc];
      float s = 0.f, s2 = 0.f;
      #pragma unroll
      for (int tj = 0; tj < 2; ++tj) {
        const int n = wnb + tj * 16 + m16;
        const size_t gidx = ((size_t)(b * COUT + oc)) * NSP + n;
        float o = fmaxf(acc[ti][tj][r] + bo, 0.f);
        float y = x[gidx] + o;        // residual: row is L1/L2-hot (B-loads)
        out[gidx] = y;                // f32, full 64B sectors per quad
        s += y;
        s2 += y * y;
      }
      #pragma unroll
      for (int d = 1; d < 16; d <<= 1) {  // stays within 16-lane group
        s  += __shfl_xor(s, d, 64);
        s2 += __shfl_xor(s2, d, 64);
      }
      if (m16 == 0) {
        atomicAdd(&ls[ocl], s);
        atomicAdd(&lq[ocl], s2);
      }
    }
  }
  __syncthreads();
  if (tid < 128) {
    atomicAdd(&stats[ocb + tid], ls[tid]);
    atomicAdd(&stats[256 + ocb + tid], lq[tid]);
  }
}

// ---------------------------------------------------------------------------
// K3: normalize d_out in place. 2048 blocks = one (b,oc) row of 2048 each.
// scale/shift computed redundantly per thread (broadcast loads).
// ---------------------------------------------------------------------------
__global__ __launch_bounds__(256) void k3_norm(
    const float* __restrict__ stats, const float* __restrict__ gamma,
    const float* __restrict__ beta, float* __restrict__ out)
{
  const int row = blockIdx.x;       // b*256 + oc
  const int oc  = row & 255;
  const float inv_n = 1.f / 16384.f;
  const float m  = stats[oc] * inv_n;
  const float v  = stats[256 + oc] * inv_n - m * m;
  const float sc = gamma[oc] * rsqrtf(v + 1e-5f);
  const float sh = beta[oc] - m * sc;
  float* p = out + (size_t)row * 2048 + threadIdx.x * 8;
  float4 a = *(const float4*)p;
  float4 c = *(const float4*)(p + 4);
  a.x = a.x * sc + sh; a.y = a.y * sc + sh;
  a.z = a.z * sc + sh; a.w = a.w * sc + sh;
  c.x = c.x * sc + sh; c.y = c.y * sc + sh;
  c.z = c.z * sc + sh; c.w = c.w * sc + sh;
  *(float4*)p = a;
  *(float4*)(p + 4) = c;
}

extern "C" void kernel_launch(void* const* d_in, const int* in_sizes, int n_in,
                              void* d_out, int out_size, void* d_ws, size_t ws_size,
                              hipStream_t stream) {
  const float* x     = (const float*)d_in[0];
  // d_in[1]=Wk, d_in[2]=Wq: dead — softmax rows sum to 1, so agg == V,
  // and o = Wout@(Wv@x) = (Wout@Wv)@x = M@x.
  const float* Wv    = (const float*)d_in[3];
  const float* Wout  = (const float*)d_in[4];
  const float* bout  = (const float*)d_in[5];
  const float* gamma = (const float*)d_in[6];
  const float* beta  = (const float*)d_in[7];
  float* out = (float*)d_out;

  char* w = (char*)d_ws;
  unsigned short* Mb = (unsigned short*)w;      // 128 KiB bf16 M
  float* stats = (float*)(w + 131072);          // 512 f32 (zeroed by K1)

  hipLaunchKernelGGL(k1_m,    dim3(256),       dim3(1024), 0, stream,
                     Wv, Wout, Mb, stats);
  hipLaunchKernelGGL(k2_gemm, dim3(32, 2, 8),  dim3(256),  0, stream,
                     x, Mb, bout, stats, out);
  hipLaunchKernelGGL(k3_norm, dim3(2048),      dim3(256),  0, stream,
                     stats, gamma, beta, out);
}